// Round 1
// baseline (225.340 us; speedup 1.0000x reference)
//
#include <hip/hip_runtime.h>
#include <math.h>

#define NCH  256
#define CROP 7

__device__ __forceinline__ float lerpf(float a, float b, float t) {
    return a + (b - a) * t;
}

// One block = 4 output pixels x 64 channel-quads (float4). grid = (13, N).
__global__ __launch_bounds__(256) void roialign_fpn_kernel(
    const float* __restrict__ p2, const float* __restrict__ p3,
    const float* __restrict__ p4, const float* __restrict__ p5,
    const float* __restrict__ rois, const int* __restrict__ bidx,
    float* __restrict__ out)
{
    const int tid = threadIdx.x;
    const int cv  = tid & 63;            // channel quad index: c = 4*cv
    const int pl  = tid >> 6;            // 0..3
    const int pix = blockIdx.x * 4 + pl; // 0..48 (52 slots, 3 idle)
    const int n   = blockIdx.y;
    if (pix >= CROP * CROP) return;
    const int jy = pix / CROP;
    const int jx = pix - jy * CROP;

    // ROI box [x1,y1,x2,y2] in image coords
    const float rx1 = rois[4*n+0];
    const float ry1 = rois[4*n+1];
    const float rx2 = rois[4*n+2];
    const float ry2 = rois[4*n+3];
    const float w = rx2 - rx1;
    const float h = ry2 - ry1;

    // level = clip(round(log2(sqrt(h*w)/224) + 4), 2, 5); jnp.round = half-to-even
    const float lvlf = logf(sqrtf(h * w) / 224.0f) / logf(2.0f) + 4.0f;
    int lvl = (int)rintf(lvlf);
    lvl = lvl < 2 ? 2 : (lvl > 5 ? 5 : lvl);
    const int i = lvl - 2;               // 0..3 -> p2..p5, stride 4<<i

    const int H = 256 >> i;              // H == W (square maps)
    const float* fm = (i == 0) ? p2 : (i == 1) ? p3 : (i == 2) ? p4 : p5;
    // ref: (roi/stride)/H ; both pow2 divisions -> exact as one reciprocal mul
    const float inv = 1.0f / (float)((4 << i) * H);
    const float Hm1 = (float)(H - 1);

    // g = j/6.0 (float division to match np bit-for-bit)
    const float gy = (float)jy / 6.0f;
    const float gx = (float)jx / 6.0f;
    const float ny1 = ry1 * inv, ny2 = ry2 * inv;
    const float nx1 = rx1 * inv, nx2 = rx2 * inv;
    const float in_y = (ny1 + (ny2 - ny1) * gy) * Hm1;
    const float in_x = (nx1 + (nx2 - nx1) * gx) * Hm1;

    const bool valid = (in_y >= 0.0f) && (in_y <= Hm1) &&
                       (in_x >= 0.0f) && (in_x <= Hm1);

    const float y0f = floorf(in_y);
    const float x0f = floorf(in_x);
    const float ly = in_y - y0f;
    const float lx = in_x - x0f;
    const int y0 = (int)fminf(fmaxf(y0f,          0.0f), Hm1);
    const int y1 = (int)fminf(fmaxf(ceilf(in_y),  0.0f), Hm1);
    const int x0 = (int)fminf(fmaxf(x0f,          0.0f), Hm1);
    const int x1 = (int)fminf(fmaxf(ceilf(in_x),  0.0f), Hm1);

    const int b = bidx[n];
    const size_t row0 = ((size_t)b * H + y0) * (size_t)H;
    const size_t row1 = ((size_t)b * H + y1) * (size_t)H;
    const int c = cv * 4;

    const float4 tl = *(const float4*)(fm + (row0 + x0) * NCH + c);
    const float4 tr = *(const float4*)(fm + (row0 + x1) * NCH + c);
    const float4 bl = *(const float4*)(fm + (row1 + x0) * NCH + c);
    const float4 br = *(const float4*)(fm + (row1 + x1) * NCH + c);

    float4 r;
    r.x = lerpf(lerpf(tl.x, tr.x, lx), lerpf(bl.x, br.x, lx), ly);
    r.y = lerpf(lerpf(tl.y, tr.y, lx), lerpf(bl.y, br.y, lx), ly);
    r.z = lerpf(lerpf(tl.z, tr.z, lx), lerpf(bl.z, br.z, lx), ly);
    r.w = lerpf(lerpf(tl.w, tr.w, lx), lerpf(bl.w, br.w, lx), ly);
    if (!valid) { r.x = 0.0f; r.y = 0.0f; r.z = 0.0f; r.w = 0.0f; }

    *(float4*)(out + ((size_t)n * (CROP * CROP) + pix) * NCH + c) = r;
}

// Second tuple output: batch_indices, written as float into the flat out tail.
__global__ void bidx_copy_kernel(const int* __restrict__ bidx,
                                 float* __restrict__ out_tail, int N)
{
    const int g = blockIdx.x * blockDim.x + threadIdx.x;
    if (g < N) out_tail[g] = (float)bidx[g];
}

extern "C" void kernel_launch(void* const* d_in, const int* in_sizes, int n_in,
                              void* d_out, int out_size, void* d_ws, size_t ws_size,
                              hipStream_t stream) {
    const float* p2   = (const float*)d_in[0];
    const float* p3   = (const float*)d_in[1];
    const float* p4   = (const float*)d_in[2];
    const float* p5   = (const float*)d_in[3];
    const float* rois = (const float*)d_in[4];
    const int*   bidx = (const int*)d_in[5];
    float* out = (float*)d_out;

    const int N = in_sizes[5];           // number of ROIs

    dim3 grid((CROP * CROP + 3) / 4, N); // (13, 1000)
    roialign_fpn_kernel<<<grid, 256, 0, stream>>>(p2, p3, p4, p5, rois, bidx, out);

    float* tail = out + (size_t)N * (CROP * CROP * NCH);
    bidx_copy_kernel<<<(N + 255) / 256, 256, 0, stream>>>(bidx, tail, N);
}